// Round 7
// baseline (557.591 us; speedup 1.0000x reference)
//
#include <hip/hip_runtime.h>
#include <math.h>

// Problem constants
#define HH 56
#define WW 56
#define NB 32
#define CC 256
#define PIX 3136               // 56*56
#define M_TOT 100352           // 32*3136
#define PADH 58
#define PADW 58
#define ACTQ_BYTES ((size_t)NB*PADH*PADW*CC)   // 27,553,792
#define WQ_BYTES ((size_t)9*CC*CC)             // 589,824
#define SBUF_BYTES ((size_t)M_TOT*CC*2)        // 51,380,224
#define BM 256
#define BN 256

typedef unsigned int u32;
typedef unsigned long long u64;
typedef int v4i __attribute__((ext_vector_type(4)));

// global_load_lds, width 16 (global -> LDS DMA; dest = wave base + lane*16)
typedef const __attribute__((address_space(1))) unsigned int* as1_u32p;
typedef __attribute__((address_space(3))) unsigned int* as3_u32p;
#define GLOAD_LDS16(g, l) \
  __builtin_amdgcn_global_load_lds((as1_u32p)(g), (as3_u32p)(l), 16, 0, 0)

// ---------------------------------------------------------------------------
// Pack weights: per-co mean (double), unbiased std, sw = 2^round(log2 mean|bw|),
// sign bytes wq[tap][co][ci] in {-1,+1}. Zeroes stat accumulators.
// ---------------------------------------------------------------------------
__global__ __launch_bounds__(256) void pack_weights_i8(
    const float* __restrict__ wt, signed char* __restrict__ wq,
    float* __restrict__ swv,
    long long* __restrict__ sumS, long long* __restrict__ sumSS) {
  int co = blockIdx.x;
  int t  = threadIdx.x;          // = ci
  int lane = t & 63, wid = t >> 6;

  float wv[9];
  const float* wp = wt + ((size_t)co*CC + t)*9;
  double psum = 0.0;
#pragma unroll
  for (int k = 0; k < 9; ++k) { wv[k] = wp[k]; psum += (double)wv[k]; }

  __shared__ double redm[4];
#pragma unroll
  for (int off = 32; off > 0; off >>= 1) psum += __shfl_xor(psum, off);
  if (lane == 0) redm[wid] = psum;
  __syncthreads();
  double mean = (redm[0]+redm[1]+redm[2]+redm[3]) * (1.0/2304.0);

  double pabs = 0.0, psq = 0.0;
#pragma unroll
  for (int k = 0; k < 9; ++k) {
    double d = (double)wv[k] - mean;
    pabs += fabs(d);
    psq  += d*d;
  }
#pragma unroll
  for (int off = 32; off > 0; off >>= 1) {
    pabs += __shfl_xor(pabs, off);
    psq  += __shfl_xor(psq,  off);
  }
  __shared__ double reda[4], redq[4];
  if (lane == 0) { reda[wid] = pabs; redq[wid] = psq; }
  __syncthreads();
  if (t == 0) {
    double sa = reda[0]+reda[1]+reda[2]+reda[3];
    double sq = redq[0]+redq[1]+redq[2]+redq[3];
    double stdv = sqrt(sq / 2303.0);                 // torch unbiased std
    double mabs = (sa * (1.0/2304.0)) / stdv;        // mean|bw|
    swv[co] = (float)exp2(rint(log2(mabs)));         // round half-to-even
    sumS[co]  = 0;
    sumSS[co] = 0;
  }
  // sign bytes: wq[k][co][ci]
#pragma unroll
  for (int k = 0; k < 9; ++k)
    wq[((size_t)k*CC + co)*CC + t] =
        (((double)wv[k] - mean) > 0.0) ? (signed char)1 : (signed char)-1;
}

// ---------------------------------------------------------------------------
// Pack activations: sign(x) -> i8 channel-last padded [n][ph][pw][ci].
// Border cells written as zeros here (memset fused away).
// ---------------------------------------------------------------------------
__global__ __launch_bounds__(256) void pack_acts_i8(
    const float* __restrict__ x, signed char* __restrict__ actq) {
  int n = blockIdx.y, tile = blockIdx.x;               // 53 tiles of 64 padded-pl
  int lane = threadIdx.x & 63, cw = threadIdx.x >> 6;  // cw: 64-ci group
  int pp = tile*64 + lane;
  if (pp >= PADH*PADW) return;
  int ph = pp / PADW, pw = pp - ph*PADW;
  signed char* dst = actq + ((size_t)(n*PADH + ph)*PADW + pw)*CC + cw*64;
  if (ph == 0 || ph == PADH-1 || pw == 0 || pw == PADW-1) {
    uint4 z = make_uint4(0u, 0u, 0u, 0u);
#pragma unroll
    for (int q = 0; q < 4; ++q) ((uint4*)dst)[q] = z;
    return;
  }
  int h = ph - 1, w = pw - 1;
  const float* xp = x + ((size_t)(n*CC + cw*64))*PIX + h*WW + w;
  u32 wrd[16];
#pragma unroll
  for (int c16 = 0; c16 < 16; ++c16) {
    u32 v = 0;
#pragma unroll
    for (int b = 0; b < 4; ++b) {
      float f = xp[(size_t)(c16*4 + b)*PIX];
      v |= (f > 0.0f ? 0x01u : 0xFFu) << (8*b);   // +1 / -1 as i8
    }
    wrd[c16] = v;
  }
#pragma unroll
  for (int q = 0; q < 4; ++q)
    ((uint4*)dst)[q] = make_uint4(wrd[4*q], wrd[4*q+1], wrd[4*q+2], wrd[4*q+3]);
}

// ---------------------------------------------------------------------------
// Binary implicit-GEMM conv, mfma_i32_16x16x64_i8.
// Round 7: 8-PHASE TEMPLATE PORT (the guide's only structure measured at
// 60%+ MfmaUtil in plain HIP). 512 thr / 8 waves, tile 256x256 (grid 392),
// wave tile 128x64 (wr=wv>>2 row half, wc=wv&3 col quarter), acc[8][4].
// 2-deep LDS (2 x 32KB: A 16K rows x 64B | B 16K cols x 64B). Each 64-K
// stage = 4 phases of 8 MFMA; per phase: {gload pair for S+1 || 2-6
// ds_reads || barrier || setprio 8xMFMA || barrier}. vmcnt(0) ONCE per
// stage at ph3 (own S+1 loads issued 2-3 phases earlier -> drain ~free;
// it must precede the ph3 barrier to give the cross-wave landed guarantee).
// sched_barrier(0) after the stage-boundary barrier pins next-stage
// ds_reads/DMA from hoisting above it (rule #18/#21). XOR chunk-swizzle
// kept (0 conflicts). Mechanism targeted: 4 waves/SIMD (2 blocks x 8
// waves) + per-phase role diversity = the m196/m218b combo.
// ---------------------------------------------------------------------------

template <bool S16>
__global__ __launch_bounds__(512, 4) void bconv_mfma(
    const signed char* __restrict__ actq, const signed char* __restrict__ wq,
    short* __restrict__ s16out, float* __restrict__ f32out,
    u64* __restrict__ sumS, u64* __restrict__ sumSS) {
  __shared__ char lds[65536] __attribute__((aligned(16)));  // 2 x (A 16K | B 16K)
  __shared__ int colS[256], colQ[256];

  int t = threadIdx.x;
  int lane = t & 63, wv = t >> 6;          // wv 0..7
  int lm = lane & 15, quad = lane >> 4;
  int wr = wv >> 2;                        // row half (0/1): rows wr*128..
  int wc = wv & 3;                         // col quarter: cols wc*64..
  int Mbase = blockIdx.x * BM;

  if (t < 256) { colS[t] = 0; colQ[t] = 0; }

  // staging: thread t -> A rows r, r+128 / B cols r, r+128 (r = t>>2),
  // 16B chunk c16 = t&3. LDS dest LINEAR; global chunk XOR-swizzled
  // cs = c16 ^ ((r>>1)&3)  (r+128 keeps the same key: 64 mod 4 == 0).
  int r = t >> 2, c16 = t & 3;
  int cs = c16 ^ ((r >> 1) & 3);
  const signed char *pA0, *pA1;
  {
    int P = Mbase + r;
    int n_ = P / PIX, pl_ = P % PIX, h_ = pl_ / WW, w_ = pl_ % WW;
    pA0 = actq + ((size_t)(n_*PADH + h_+1)*PADW + (w_+1))*CC + cs*16;
    P += 128;
    n_ = P / PIX; pl_ = P % PIX; h_ = pl_ / WW; w_ = pl_ % WW;
    pA1 = actq + ((size_t)(n_*PADH + h_+1)*PADW + (w_+1))*CC + cs*16;
  }
  const signed char* pB0 = wq + (size_t)r*CC + cs*16;
  const signed char* pB1 = pB0 + 128*CC;
  int ldst = t*16;

  // read side: lane (lm,quad) wants global chunk=quad of row base+lm ->
  // LDS slot quad ^ ((row>>1)&3) == quad ^ ((lm>>1)&3) for 16-aligned bases
  int rdo = (quad ^ ((lm >> 1) & 3)) * 16;

  v4i acc[8][4];
#pragma unroll
  for (int i = 0; i < 8; ++i)
#pragma unroll
    for (int j = 0; j < 4; ++j) acc[i][j] = 0;

// stage SN staging halves (A: 2 gloads; B: 2 gloads) into buf[SN&1]
#define STAGE_A(SN) do {                                                  \
    int tn_ = (SN) >> 2, kn_ = (SN) & 3;                                  \
    int aoff_ = ((tn_/3 - 1)*PADW + (tn_%3 - 1))*CC + kn_*64;             \
    char* nb_ = (char*)lds + (((SN) & 1) << 15);                          \
    GLOAD_LDS16(pA0 + aoff_, nb_ + ldst);                                 \
    GLOAD_LDS16(pA1 + aoff_, nb_ + 8192 + ldst);                          \
  } while (0)
#define STAGE_B(SN) do {                                                  \
    int tn_ = (SN) >> 2, kn_ = (SN) & 3;                                  \
    int boff_ = tn_*65536 + kn_*64;                                       \
    char* nb_ = (char*)lds + (((SN) & 1) << 15);                          \
    GLOAD_LDS16(pB0 + boff_, nb_ + 16384 + ldst);                         \
    GLOAD_LDS16(pB1 + boff_, nb_ + 24576 + ldst);                         \
  } while (0)
#define MFMA8(I0, J0) do {                                                \
    __builtin_amdgcn_s_setprio(1);                                        \
    _Pragma("unroll")                                                     \
    for (int i_ = 0; i_ < 4; ++i_)                                        \
      _Pragma("unroll")                                                   \
      for (int j_ = 0; j_ < 2; ++j_)                                      \
        acc[(I0)+i_][(J0)+j_] = __builtin_amdgcn_mfma_i32_16x16x64_i8(    \
            af[(I0)+i_], bf[(J0)+j_], acc[(I0)+i_][(J0)+j_], 0, 0, 0);    \
    __builtin_amdgcn_s_setprio(0);                                        \
  } while (0)

  // prologue: stage 0 fully, drain, barrier
  STAGE_A(0);
  STAGE_B(0);
  asm volatile("s_waitcnt vmcnt(0)" ::: "memory");
  __builtin_amdgcn_s_barrier();
  __builtin_amdgcn_sched_barrier(0);

  // 36 stages (tap = s>>2, kq = s&3), 4 phases of 8 MFMA each
#pragma unroll 1
  for (int s = 0; s < 36; ++s) {
    const char* cb_ = (const char*)lds + ((s & 1) << 15);
    bool dostage = (s < 35);
    v4i af[8], bf[4];
    // ---- phase 0: A(S+1) gloads; af[0..3], bf[0..1]; MFMA (i0-3 x j0-1)
    if (dostage) STAGE_A(s + 1);
#pragma unroll
    for (int i = 0; i < 4; ++i)
      af[i] = *(const v4i*)(cb_ + (wr*128 + i*16 + lm)*64 + rdo);
#pragma unroll
    for (int j = 0; j < 2; ++j)
      bf[j] = *(const v4i*)(cb_ + 16384 + (wc*64 + j*16 + lm)*64 + rdo);
    __builtin_amdgcn_s_barrier();
    MFMA8(0, 0);
    __builtin_amdgcn_s_barrier();
    // ---- phase 1: B(S+1) gloads; bf[2..3]; MFMA (i0-3 x j2-3)
    if (dostage) STAGE_B(s + 1);
#pragma unroll
    for (int j = 2; j < 4; ++j)
      bf[j] = *(const v4i*)(cb_ + 16384 + (wc*64 + j*16 + lm)*64 + rdo);
    __builtin_amdgcn_s_barrier();
    MFMA8(0, 2);
    __builtin_amdgcn_s_barrier();
    // ---- phase 2: af[4..7]; MFMA (i4-7 x j0-1)
#pragma unroll
    for (int i = 4; i < 8; ++i)
      af[i] = *(const v4i*)(cb_ + (wr*128 + i*16 + lm)*64 + rdo);
    __builtin_amdgcn_s_barrier();
    MFMA8(4, 0);
    __builtin_amdgcn_s_barrier();
    // ---- phase 3: MFMA (i4-7 x j2-3); own S+1 loads drained; barrier
    MFMA8(4, 2);
    asm volatile("s_waitcnt vmcnt(0)" ::: "memory");
    __builtin_amdgcn_s_barrier();
    __builtin_amdgcn_sched_barrier(0);   // pin next-stage reads/DMA below
  }

  // ---- epilogue: store s16 (tile-local layout) / f32 + per-channel stats ----
  int Sl[4] = {0,0,0,0}, Ql[4] = {0,0,0,0};
  if (S16) {
    // sbuf layout: [tile 392][col 0..255][row 0..255] shorts; dense writes.
    short* tb = s16out + (size_t)blockIdx.x * (BM*BN);
#pragma unroll
    for (int i = 0; i < 8; ++i) {
      int rhat = wr*128 + i*16 + quad*4;   // rows rhat..rhat+3 (4-aligned)
#pragma unroll
      for (int j = 0; j < 4; ++j) {
        int colo = wc*64 + j*16 + lm;
        v4i a = acc[i][j];
        int2 pk;
        pk.x = (a.x & 0xFFFF) | (a.y << 16);
        pk.y = (a.z & 0xFFFF) | (a.w << 16);
        *(int2*)(tb + (size_t)colo*BM + rhat) = pk;
        Sl[j] += a.x + a.y + a.z + a.w;
        Ql[j] += a.x*a.x + a.y*a.y + a.z*a.z + a.w*a.w;
      }
    }
  } else {
#pragma unroll
    for (int i = 0; i < 8; ++i) {
      int R = Mbase + wr*128 + i*16 + quad*4;   // rows R..R+3 (PIX%4==0)
      int nR = R / PIX, plR = R % PIX;
#pragma unroll
      for (int j = 0; j < 4; ++j) {
        int colo = wc*64 + j*16 + lm;
        v4i a = acc[i][j];
        size_t idx = ((size_t)nR*CC + colo)*PIX + plR;
        *(float4*)(f32out + idx) =
            make_float4((float)a.x, (float)a.y, (float)a.z, (float)a.w);
        Sl[j] += a.x + a.y + a.z + a.w;
        Ql[j] += a.x*a.x + a.y*a.y + a.z*a.z + a.w*a.w;
      }
    }
  }
#pragma unroll
  for (int j = 0; j < 4; ++j) {
    int S = Sl[j], Q = Ql[j];
    S += __shfl_xor(S, 16); S += __shfl_xor(S, 32);   // reduce over quads
    Q += __shfl_xor(Q, 16); Q += __shfl_xor(Q, 32);
    if (quad == 0) {
      atomicAdd(&colS[wc*64 + j*16 + lm], S);
      atomicAdd(&colQ[wc*64 + j*16 + lm], Q);
    }
  }
  __syncthreads();
  if (t < 256) {
    atomicAdd(&sumS[t], (u64)(long long)colS[t]);   // 2's-comp wrap ok
    atomicAdd(&sumSS[t], (u64)(long long)colQ[t]);
  }
}

// ---------------------------------------------------------------------------
// Per-channel BN fold: out = clip(s*A + B)
// ---------------------------------------------------------------------------
__global__ void finalize_stats(
    const long long* __restrict__ sumS, const long long* __restrict__ sumSS,
    const float* __restrict__ swv,
    const float* __restrict__ gamma, const float* __restrict__ beta,
    float* __restrict__ AB) {
  int c = threadIdx.x;
  double mu  = (double)sumS[c]  / (double)M_TOT;
  double var = (double)sumSS[c] / (double)M_TOT - mu*mu;
  double sw  = (double)swv[c];
  double inv = 1.0 / sqrt(sw*sw*var + 1e-5);
  double scale = (double)gamma[c] * sw * inv;
  double shift = (double)beta[c] - scale * mu;
  AB[c]      = (float)scale;
  AB[CC + c] = (float)shift;
}

// Reads sbuf in tile-local layout [tile][col 256][row 256]; writes NCHW f32.
__global__ __launch_bounds__(256) void bn_apply_s16(
    const short* __restrict__ s, float* __restrict__ out,
    const float* __restrict__ AB, int n8) {
  int i = blockIdx.x*256 + threadIdx.x;
  if (i >= n8) return;
  union { int4 v; short sh[8]; } u;
  u.v = ((const int4*)s)[i];
  int base   = i*8;
  int tile   = base >> 16;          // BM*BN = 65536 shorts per tile
  int within = base & 65535;
  int col    = within >> 8;         // 0..255  (channel)
  int rh     = within & 255;        // row in tile, multiple of 8
  int R  = tile*BM + rh;            // global M index; 8-row group never
  int n_ = R / PIX, pl = R % PIX;   // straddles n (PIX%8==0, BM%8==0)
  float a = AB[col], b = AB[CC + col];
  float* op = out + ((size_t)n_*CC + col)*PIX + pl;
  float4 o0, o1;
  o0.x = fminf(1.f, fmaxf(-1.f, (float)u.sh[0]*a + b));
  o0.y = fminf(1.f, fmaxf(-1.f, (float)u.sh[1]*a + b));
  o0.z = fminf(1.f, fmaxf(-1.f, (float)u.sh[2]*a + b));
  o0.w = fminf(1.f, fmaxf(-1.f, (float)u.sh[3]*a + b));
  o1.x = fminf(1.f, fmaxf(-1.f, (float)u.sh[4]*a + b));
  o1.y = fminf(1.f, fmaxf(-1.f, (float)u.sh[5]*a + b));
  o1.z = fminf(1.f, fmaxf(-1.f, (float)u.sh[6]*a + b));
  o1.w = fminf(1.f, fmaxf(-1.f, (float)u.sh[7]*a + b));
  ((float4*)op)[0] = o0;
  ((float4*)op)[1] = o1;
}

__global__ __launch_bounds__(256) void bn_apply_f32(
    float* __restrict__ out, const float* __restrict__ AB, int n4) {
  int i = blockIdx.x*256 + threadIdx.x;
  if (i >= n4) return;
  float4 v = ((float4*)out)[i];
  int c = ((i*4) / PIX) & (CC-1);
  float a = AB[c], b = AB[CC + c];
  v.x = fminf(1.f, fmaxf(-1.f, v.x*a + b));
  v.y = fminf(1.f, fmaxf(-1.f, v.y*a + b));
  v.z = fminf(1.f, fmaxf(-1.f, v.z*a + b));
  v.w = fminf(1.f, fmaxf(-1.f, v.w*a + b));
  ((float4*)out)[i] = v;
}

extern "C" void kernel_launch(void* const* d_in, const int* in_sizes, int n_in,
                              void* d_out, int out_size, void* d_ws, size_t ws_size,
                              hipStream_t stream) {
  (void)in_sizes; (void)n_in; (void)out_size;
  const float* x     = (const float*)d_in[0];
  const float* wt    = (const float*)d_in[1];
  const float* gamma = (const float*)d_in[2];
  const float* beta  = (const float*)d_in[3];
  float* out = (float*)d_out;

  char* ws = (char*)d_ws;
  size_t off = 0;
  signed char* actq = (signed char*)(ws + off);
  off += ACTQ_BYTES;             off = (off + 255) & ~(size_t)255;
  signed char* wq = (signed char*)(ws + off);
  off += WQ_BYTES;               off = (off + 255) & ~(size_t)255;
  float* swv = (float*)(ws + off); off += 1024;
  float* AB  = (float*)(ws + off); off += 2048;
  long long* sumS  = (long long*)(ws + off); off += 2048;
  long long* sumSS = (long long*)(ws + off); off += 2048;
  off = (off + 255) & ~(size_t)255;
  short* sbuf = (short*)(ws + off);
  bool s16 = (ws_size >= off + SBUF_BYTES);

  pack_weights_i8<<<256, 256, 0, stream>>>(wt, wq, swv, sumS, sumSS);
  pack_acts_i8<<<dim3(53, NB), 256, 0, stream>>>(x, actq);  // borders zeroed here
  if (s16) {
    bconv_mfma<true><<<dim3(M_TOT/BM, 1), 512, 0, stream>>>(
        actq, wq, sbuf, nullptr, (u64*)sumS, (u64*)sumSS);
  } else {
    bconv_mfma<false><<<dim3(M_TOT/BM, 1), 512, 0, stream>>>(
        actq, wq, nullptr, out, (u64*)sumS, (u64*)sumSS);
  }
  finalize_stats<<<1, 256, 0, stream>>>(sumS, sumSS, swv, gamma, beta, AB);
  if (s16) {
    bn_apply_s16<<<(M_TOT*CC/8 + 255)/256, 256, 0, stream>>>(
        sbuf, out, AB, M_TOT*CC/8);
  } else {
    bn_apply_f32<<<(M_TOT*CC/4 + 255)/256, 256, 0, stream>>>(
        out, AB, M_TOT*CC/4);
  }
}

// Round 8
// 189.530 us; speedup vs baseline: 2.9420x; 2.9420x over previous
//
#include <hip/hip_runtime.h>
#include <math.h>

// Problem constants
#define HH 56
#define WW 56
#define NB 32
#define CC 256
#define PIX 3136               // 56*56
#define M_TOT 100352           // 32*3136
#define PADH 58
#define PADW 58
#define ACTQ_BYTES ((size_t)NB*PADH*PADW*CC)   // 27,553,792
#define WQ_BYTES ((size_t)9*CC*CC)             // 589,824
#define SBUF_BYTES ((size_t)M_TOT*CC*2)        // 51,380,224
#define BM 256
#define BN 256

typedef unsigned int u32;
typedef unsigned long long u64;
typedef int v4i __attribute__((ext_vector_type(4)));

// global_load_lds, width 16 (global -> LDS DMA; dest = wave base + lane*16)
typedef const __attribute__((address_space(1))) unsigned int* as1_u32p;
typedef __attribute__((address_space(3))) unsigned int* as3_u32p;
#define GLOAD_LDS16(g, l) \
  __builtin_amdgcn_global_load_lds((as1_u32p)(g), (as3_u32p)(l), 16, 0, 0)

// ---------------------------------------------------------------------------
// Pack weights: per-co mean (double), unbiased std, sw = 2^round(log2 mean|bw|),
// sign bytes wq[tap][co][ci] in {-1,+1}. Zeroes stat accumulators.
// ---------------------------------------------------------------------------
__global__ __launch_bounds__(256) void pack_weights_i8(
    const float* __restrict__ wt, signed char* __restrict__ wq,
    float* __restrict__ swv,
    long long* __restrict__ sumS, long long* __restrict__ sumSS) {
  int co = blockIdx.x;
  int t  = threadIdx.x;          // = ci
  int lane = t & 63, wid = t >> 6;

  float wv[9];
  const float* wp = wt + ((size_t)co*CC + t)*9;
  double psum = 0.0;
#pragma unroll
  for (int k = 0; k < 9; ++k) { wv[k] = wp[k]; psum += (double)wv[k]; }

  __shared__ double redm[4];
#pragma unroll
  for (int off = 32; off > 0; off >>= 1) psum += __shfl_xor(psum, off);
  if (lane == 0) redm[wid] = psum;
  __syncthreads();
  double mean = (redm[0]+redm[1]+redm[2]+redm[3]) * (1.0/2304.0);

  double pabs = 0.0, psq = 0.0;
#pragma unroll
  for (int k = 0; k < 9; ++k) {
    double d = (double)wv[k] - mean;
    pabs += fabs(d);
    psq  += d*d;
  }
#pragma unroll
  for (int off = 32; off > 0; off >>= 1) {
    pabs += __shfl_xor(pabs, off);
    psq  += __shfl_xor(psq,  off);
  }
  __shared__ double reda[4], redq[4];
  if (lane == 0) { reda[wid] = pabs; redq[wid] = psq; }
  __syncthreads();
  if (t == 0) {
    double sa = reda[0]+reda[1]+reda[2]+reda[3];
    double sq = redq[0]+redq[1]+redq[2]+redq[3];
    double stdv = sqrt(sq / 2303.0);                 // torch unbiased std
    double mabs = (sa * (1.0/2304.0)) / stdv;        // mean|bw|
    swv[co] = (float)exp2(rint(log2(mabs)));         // round half-to-even
    sumS[co]  = 0;
    sumSS[co] = 0;
  }
  // sign bytes: wq[k][co][ci]
#pragma unroll
  for (int k = 0; k < 9; ++k)
    wq[((size_t)k*CC + co)*CC + t] =
        (((double)wv[k] - mean) > 0.0) ? (signed char)1 : (signed char)-1;
}

// ---------------------------------------------------------------------------
// Pack activations: sign(x) -> i8 channel-last padded [n][ph][pw][ci].
// Border cells written as zeros here (memset fused away).
// ---------------------------------------------------------------------------
__global__ __launch_bounds__(256) void pack_acts_i8(
    const float* __restrict__ x, signed char* __restrict__ actq) {
  int n = blockIdx.y, tile = blockIdx.x;               // 53 tiles of 64 padded-pl
  int lane = threadIdx.x & 63, cw = threadIdx.x >> 6;  // cw: 64-ci group
  int pp = tile*64 + lane;
  if (pp >= PADH*PADW) return;
  int ph = pp / PADW, pw = pp - ph*PADW;
  signed char* dst = actq + ((size_t)(n*PADH + ph)*PADW + pw)*CC + cw*64;
  if (ph == 0 || ph == PADH-1 || pw == 0 || pw == PADW-1) {
    uint4 z = make_uint4(0u, 0u, 0u, 0u);
#pragma unroll
    for (int q = 0; q < 4; ++q) ((uint4*)dst)[q] = z;
    return;
  }
  int h = ph - 1, w = pw - 1;
  const float* xp = x + ((size_t)(n*CC + cw*64))*PIX + h*WW + w;
  u32 wrd[16];
#pragma unroll
  for (int c16 = 0; c16 < 16; ++c16) {
    u32 v = 0;
#pragma unroll
    for (int b = 0; b < 4; ++b) {
      float f = xp[(size_t)(c16*4 + b)*PIX];
      v |= (f > 0.0f ? 0x01u : 0xFFu) << (8*b);   // +1 / -1 as i8
    }
    wrd[c16] = v;
  }
#pragma unroll
  for (int q = 0; q < 4; ++q)
    ((uint4*)dst)[q] = make_uint4(wrd[4*q], wrd[4*q+1], wrd[4*q+2], wrd[4*q+3]);
}

// ---------------------------------------------------------------------------
// Binary implicit-GEMM conv, mfma_i32_16x16x64_i8.
// Round 8: R7's 8-phase structure with the SPILL BUG FIXED. R7 declared
// __launch_bounds__(512, 4) = 4 waves/SIMD min -> 128-VGPR cap -> the
// 128-VGPR accumulator spilled to scratch (VGPR_Count=64, FETCH 899MB,
// 497us). Now __launch_bounds__(512, 2) -> 256-VGPR cap, ~220 live regs,
// 2 blocks/CU (LDS 67.6KB) = 16 waves/CU. Structure unchanged from R7:
// 512 thr / 8 waves, tile 256x256 (grid 392), wave tile 128x64, acc[8][4],
// 2-deep LDS, 4 phases x 8 MFMA per 64-K stage, per-phase {gload-pair ||
// ds_reads || barrier || setprio MFMA || barrier}, vmcnt(0) once per stage
// at ph3, sched_barrier(0) at stage boundary. XOR chunk-swizzle kept.
// ---------------------------------------------------------------------------

template <bool S16>
__global__ __launch_bounds__(512, 2) void bconv_mfma(
    const signed char* __restrict__ actq, const signed char* __restrict__ wq,
    short* __restrict__ s16out, float* __restrict__ f32out,
    u64* __restrict__ sumS, u64* __restrict__ sumSS) {
  __shared__ char lds[65536] __attribute__((aligned(16)));  // 2 x (A 16K | B 16K)
  __shared__ int colS[256], colQ[256];

  int t = threadIdx.x;
  int lane = t & 63, wv = t >> 6;          // wv 0..7
  int lm = lane & 15, quad = lane >> 4;
  int wr = wv >> 2;                        // row half (0/1): rows wr*128..
  int wc = wv & 3;                         // col quarter: cols wc*64..
  int Mbase = blockIdx.x * BM;

  if (t < 256) { colS[t] = 0; colQ[t] = 0; }

  // staging: thread t -> A rows r, r+128 / B cols r, r+128 (r = t>>2),
  // 16B chunk c16 = t&3. LDS dest LINEAR; global chunk XOR-swizzled
  // cs = c16 ^ ((r>>1)&3)  (r+128 keeps the same key: 64 mod 4 == 0).
  int r = t >> 2, c16 = t & 3;
  int cs = c16 ^ ((r >> 1) & 3);
  const signed char *pA0, *pA1;
  {
    int P = Mbase + r;
    int n_ = P / PIX, pl_ = P % PIX, h_ = pl_ / WW, w_ = pl_ % WW;
    pA0 = actq + ((size_t)(n_*PADH + h_+1)*PADW + (w_+1))*CC + cs*16;
    P += 128;
    n_ = P / PIX; pl_ = P % PIX; h_ = pl_ / WW; w_ = pl_ % WW;
    pA1 = actq + ((size_t)(n_*PADH + h_+1)*PADW + (w_+1))*CC + cs*16;
  }
  const signed char* pB0 = wq + (size_t)r*CC + cs*16;
  const signed char* pB1 = pB0 + 128*CC;
  int ldst = t*16;

  // read side: lane (lm,quad) wants global chunk=quad of row base+lm ->
  // LDS slot quad ^ ((row>>1)&3) == quad ^ ((lm>>1)&3) for 16-aligned bases
  int rdo = (quad ^ ((lm >> 1) & 3)) * 16;

  v4i acc[8][4];
#pragma unroll
  for (int i = 0; i < 8; ++i)
#pragma unroll
    for (int j = 0; j < 4; ++j) acc[i][j] = 0;

// stage SN staging halves (A: 2 gloads; B: 2 gloads) into buf[SN&1]
#define STAGE_A(SN) do {                                                  \
    int tn_ = (SN) >> 2, kn_ = (SN) & 3;                                  \
    int aoff_ = ((tn_/3 - 1)*PADW + (tn_%3 - 1))*CC + kn_*64;             \
    char* nb_ = (char*)lds + (((SN) & 1) << 15);                          \
    GLOAD_LDS16(pA0 + aoff_, nb_ + ldst);                                 \
    GLOAD_LDS16(pA1 + aoff_, nb_ + 8192 + ldst);                          \
  } while (0)
#define STAGE_B(SN) do {                                                  \
    int tn_ = (SN) >> 2, kn_ = (SN) & 3;                                  \
    int boff_ = tn_*65536 + kn_*64;                                       \
    char* nb_ = (char*)lds + (((SN) & 1) << 15);                          \
    GLOAD_LDS16(pB0 + boff_, nb_ + 16384 + ldst);                         \
    GLOAD_LDS16(pB1 + boff_, nb_ + 24576 + ldst);                         \
  } while (0)
#define MFMA8(I0, J0) do {                                                \
    __builtin_amdgcn_s_setprio(1);                                        \
    _Pragma("unroll")                                                     \
    for (int i_ = 0; i_ < 4; ++i_)                                        \
      _Pragma("unroll")                                                   \
      for (int j_ = 0; j_ < 2; ++j_)                                      \
        acc[(I0)+i_][(J0)+j_] = __builtin_amdgcn_mfma_i32_16x16x64_i8(    \
            af[(I0)+i_], bf[(J0)+j_], acc[(I0)+i_][(J0)+j_], 0, 0, 0);    \
    __builtin_amdgcn_s_setprio(0);                                        \
  } while (0)

  // prologue: stage 0 fully, drain, barrier
  STAGE_A(0);
  STAGE_B(0);
  asm volatile("s_waitcnt vmcnt(0)" ::: "memory");
  __builtin_amdgcn_s_barrier();
  __builtin_amdgcn_sched_barrier(0);

  // 36 stages (tap = s>>2, kq = s&3), 4 phases of 8 MFMA each
#pragma unroll 1
  for (int s = 0; s < 36; ++s) {
    const char* cb_ = (const char*)lds + ((s & 1) << 15);
    bool dostage = (s < 35);
    v4i af[8], bf[4];
    // ---- phase 0: A(S+1) gloads; af[0..3], bf[0..1]; MFMA (i0-3 x j0-1)
    if (dostage) STAGE_A(s + 1);
#pragma unroll
    for (int i = 0; i < 4; ++i)
      af[i] = *(const v4i*)(cb_ + (wr*128 + i*16 + lm)*64 + rdo);
#pragma unroll
    for (int j = 0; j < 2; ++j)
      bf[j] = *(const v4i*)(cb_ + 16384 + (wc*64 + j*16 + lm)*64 + rdo);
    __builtin_amdgcn_s_barrier();
    MFMA8(0, 0);
    __builtin_amdgcn_s_barrier();
    // ---- phase 1: B(S+1) gloads; bf[2..3]; MFMA (i0-3 x j2-3)
    if (dostage) STAGE_B(s + 1);
#pragma unroll
    for (int j = 2; j < 4; ++j)
      bf[j] = *(const v4i*)(cb_ + 16384 + (wc*64 + j*16 + lm)*64 + rdo);
    __builtin_amdgcn_s_barrier();
    MFMA8(0, 2);
    __builtin_amdgcn_s_barrier();
    // ---- phase 2: af[4..7]; MFMA (i4-7 x j0-1)
#pragma unroll
    for (int i = 4; i < 8; ++i)
      af[i] = *(const v4i*)(cb_ + (wr*128 + i*16 + lm)*64 + rdo);
    __builtin_amdgcn_s_barrier();
    MFMA8(4, 0);
    __builtin_amdgcn_s_barrier();
    // ---- phase 3: MFMA (i4-7 x j2-3); own S+1 loads drained; barrier
    MFMA8(4, 2);
    asm volatile("s_waitcnt vmcnt(0)" ::: "memory");
    __builtin_amdgcn_s_barrier();
    __builtin_amdgcn_sched_barrier(0);   // pin next-stage reads/DMA below
  }

  // ---- epilogue: store s16 (tile-local layout) / f32 + per-channel stats ----
  int Sl[4] = {0,0,0,0}, Ql[4] = {0,0,0,0};
  if (S16) {
    // sbuf layout: [tile 392][col 0..255][row 0..255] shorts; dense writes.
    short* tb = s16out + (size_t)blockIdx.x * (BM*BN);
#pragma unroll
    for (int i = 0; i < 8; ++i) {
      int rhat = wr*128 + i*16 + quad*4;   // rows rhat..rhat+3 (4-aligned)
#pragma unroll
      for (int j = 0; j < 4; ++j) {
        int colo = wc*64 + j*16 + lm;
        v4i a = acc[i][j];
        int2 pk;
        pk.x = (a.x & 0xFFFF) | (a.y << 16);
        pk.y = (a.z & 0xFFFF) | (a.w << 16);
        *(int2*)(tb + (size_t)colo*BM + rhat) = pk;
        Sl[j] += a.x + a.y + a.z + a.w;
        Ql[j] += a.x*a.x + a.y*a.y + a.z*a.z + a.w*a.w;
      }
    }
  } else {
#pragma unroll
    for (int i = 0; i < 8; ++i) {
      int R = Mbase + wr*128 + i*16 + quad*4;   // rows R..R+3 (PIX%4==0)
      int nR = R / PIX, plR = R % PIX;
#pragma unroll
      for (int j = 0; j < 4; ++j) {
        int colo = wc*64 + j*16 + lm;
        v4i a = acc[i][j];
        size_t idx = ((size_t)nR*CC + colo)*PIX + plR;
        *(float4*)(f32out + idx) =
            make_float4((float)a.x, (float)a.y, (float)a.z, (float)a.w);
        Sl[j] += a.x + a.y + a.z + a.w;
        Ql[j] += a.x*a.x + a.y*a.y + a.z*a.z + a.w*a.w;
      }
    }
  }
#pragma unroll
  for (int j = 0; j < 4; ++j) {
    int S = Sl[j], Q = Ql[j];
    S += __shfl_xor(S, 16); S += __shfl_xor(S, 32);   // reduce over quads
    Q += __shfl_xor(Q, 16); Q += __shfl_xor(Q, 32);
    if (quad == 0) {
      atomicAdd(&colS[wc*64 + j*16 + lm], S);
      atomicAdd(&colQ[wc*64 + j*16 + lm], Q);
    }
  }
  __syncthreads();
  if (t < 256) {
    atomicAdd(&sumS[t], (u64)(long long)colS[t]);   // 2's-comp wrap ok
    atomicAdd(&sumSS[t], (u64)(long long)colQ[t]);
  }
}

// ---------------------------------------------------------------------------
// Per-channel BN fold: out = clip(s*A + B)
// ---------------------------------------------------------------------------
__global__ void finalize_stats(
    const long long* __restrict__ sumS, const long long* __restrict__ sumSS,
    const float* __restrict__ swv,
    const float* __restrict__ gamma, const float* __restrict__ beta,
    float* __restrict__ AB) {
  int c = threadIdx.x;
  double mu  = (double)sumS[c]  / (double)M_TOT;
  double var = (double)sumSS[c] / (double)M_TOT - mu*mu;
  double sw  = (double)swv[c];
  double inv = 1.0 / sqrt(sw*sw*var + 1e-5);
  double scale = (double)gamma[c] * sw * inv;
  double shift = (double)beta[c] - scale * mu;
  AB[c]      = (float)scale;
  AB[CC + c] = (float)shift;
}

// Reads sbuf in tile-local layout [tile][col 256][row 256]; writes NCHW f32.
__global__ __launch_bounds__(256) void bn_apply_s16(
    const short* __restrict__ s, float* __restrict__ out,
    const float* __restrict__ AB, int n8) {
  int i = blockIdx.x*256 + threadIdx.x;
  if (i >= n8) return;
  union { int4 v; short sh[8]; } u;
  u.v = ((const int4*)s)[i];
  int base   = i*8;
  int tile   = base >> 16;          // BM*BN = 65536 shorts per tile
  int within = base & 65535;
  int col    = within >> 8;         // 0..255  (channel)
  int rh     = within & 255;        // row in tile, multiple of 8
  int R  = tile*BM + rh;            // global M index; 8-row group never
  int n_ = R / PIX, pl = R % PIX;   // straddles n (PIX%8==0, BM%8==0)
  float a = AB[col], b = AB[CC + col];
  float* op = out + ((size_t)n_*CC + col)*PIX + pl;
  float4 o0, o1;
  o0.x = fminf(1.f, fmaxf(-1.f, (float)u.sh[0]*a + b));
  o0.y = fminf(1.f, fmaxf(-1.f, (float)u.sh[1]*a + b));
  o0.z = fminf(1.f, fmaxf(-1.f, (float)u.sh[2]*a + b));
  o0.w = fminf(1.f, fmaxf(-1.f, (float)u.sh[3]*a + b));
  o1.x = fminf(1.f, fmaxf(-1.f, (float)u.sh[4]*a + b));
  o1.y = fminf(1.f, fmaxf(-1.f, (float)u.sh[5]*a + b));
  o1.z = fminf(1.f, fmaxf(-1.f, (float)u.sh[6]*a + b));
  o1.w = fminf(1.f, fmaxf(-1.f, (float)u.sh[7]*a + b));
  ((float4*)op)[0] = o0;
  ((float4*)op)[1] = o1;
}

__global__ __launch_bounds__(256) void bn_apply_f32(
    float* __restrict__ out, const float* __restrict__ AB, int n4) {
  int i = blockIdx.x*256 + threadIdx.x;
  if (i >= n4) return;
  float4 v = ((float4*)out)[i];
  int c = ((i*4) / PIX) & (CC-1);
  float a = AB[c], b = AB[CC + c];
  v.x = fminf(1.f, fmaxf(-1.f, v.x*a + b));
  v.y = fminf(1.f, fmaxf(-1.f, v.y*a + b));
  v.z = fminf(1.f, fmaxf(-1.f, v.z*a + b));
  v.w = fminf(1.f, fmaxf(-1.f, v.w*a + b));
  ((float4*)out)[i] = v;
}

extern "C" void kernel_launch(void* const* d_in, const int* in_sizes, int n_in,
                              void* d_out, int out_size, void* d_ws, size_t ws_size,
                              hipStream_t stream) {
  (void)in_sizes; (void)n_in; (void)out_size;
  const float* x     = (const float*)d_in[0];
  const float* wt    = (const float*)d_in[1];
  const float* gamma = (const float*)d_in[2];
  const float* beta  = (const float*)d_in[3];
  float* out = (float*)d_out;

  char* ws = (char*)d_ws;
  size_t off = 0;
  signed char* actq = (signed char*)(ws + off);
  off += ACTQ_BYTES;             off = (off + 255) & ~(size_t)255;
  signed char* wq = (signed char*)(ws + off);
  off += WQ_BYTES;               off = (off + 255) & ~(size_t)255;
  float* swv = (float*)(ws + off); off += 1024;
  float* AB  = (float*)(ws + off); off += 2048;
  long long* sumS  = (long long*)(ws + off); off += 2048;
  long long* sumSS = (long long*)(ws + off); off += 2048;
  off = (off + 255) & ~(size_t)255;
  short* sbuf = (short*)(ws + off);
  bool s16 = (ws_size >= off + SBUF_BYTES);

  pack_weights_i8<<<256, 256, 0, stream>>>(wt, wq, swv, sumS, sumSS);
  pack_acts_i8<<<dim3(53, NB), 256, 0, stream>>>(x, actq);  // borders zeroed here
  if (s16) {
    bconv_mfma<true><<<dim3(M_TOT/BM, 1), 512, 0, stream>>>(
        actq, wq, sbuf, nullptr, (u64*)sumS, (u64*)sumSS);
  } else {
    bconv_mfma<false><<<dim3(M_TOT/BM, 1), 512, 0, stream>>>(
        actq, wq, nullptr, out, (u64*)sumS, (u64*)sumSS);
  }
  finalize_stats<<<1, 256, 0, stream>>>(sumS, sumSS, swv, gamma, beta, AB);
  if (s16) {
    bn_apply_s16<<<(M_TOT*CC/8 + 255)/256, 256, 0, stream>>>(
        sbuf, out, AB, M_TOT*CC/8);
  } else {
    bn_apply_f32<<<(M_TOT*CC/4 + 255)/256, 256, 0, stream>>>(
        out, AB, M_TOT*CC/4);
  }
}